// Round 7
// baseline (1581.440 us; speedup 1.0000x reference)
//
#include <hip/hip_runtime.h>

// Sinkhorn [B=32, N=1024, M=1024], 15 alternating normalizations, eps=1e-4.
// Factorized: s_k = diag(r_k)*S0*diag(c_k). Single PERSISTENT kernel:
// 1024 blocks (4/CU guaranteed by __launch_bounds__(256,4); 1024 = 4*256 so
// all blocks co-resident -> hand-rolled device-scope grid barrier is safe).
// Block (b=bid%32, chunk=bid/32) owns rows [32*chunk,32*chunk+32) of batch b
// for the whole run: r,v in LDS, c (4 cols/thread) in registers, fp16 copy
// of its S0 slice written once and re-read 15x (block-private => natural L2
// locality). Only cross-block data: upart column-sum partials (4 MB, double-
// buffered => one barrier per colsum->rowsum edge, 8 total).
// Phase 0 reads fp32 S0, emits fp16 sh. Final reads sh, writes out (NT).

#define EPSF 1e-4f
constexpr int B_      = 32;
constexpr int N_      = 1024;
constexpr int M_      = 1024;
constexpr int ICHUNK  = 32;
constexpr int NCHUNKS = N_ / ICHUNK;    // 32
constexpr int THREADS = 256;
constexpr int NBLOCKS = B_ * NCHUNKS;   // 1024 = 4 blocks/CU * 256 CUs

typedef _Float16 half4v __attribute__((ext_vector_type(4)));
typedef _Float16 half8v __attribute__((ext_vector_type(8)));
typedef float    f32x4  __attribute__((ext_vector_type(4)));

// Sense-reversing grid barrier, device scope. bar[0]=arrive count, bar[1]=gen.
// Release-sequence on bar[0] + release/acquire on bar[1] orders all blocks'
// prior global writes before any block's post-barrier reads.
__device__ __forceinline__ void gridBarrier(unsigned* bar, unsigned gen)
{
    __syncthreads();
    if (threadIdx.x == 0) {
        unsigned old = __hip_atomic_fetch_add(&bar[0], 1u, __ATOMIC_ACQ_REL,
                                              __HIP_MEMORY_SCOPE_AGENT);
        if (old == (unsigned)(NBLOCKS - 1)) {
            __hip_atomic_store(&bar[0], 0u, __ATOMIC_RELAXED,
                               __HIP_MEMORY_SCOPE_AGENT);
            __hip_atomic_fetch_add(&bar[1], 1u, __ATOMIC_RELEASE,
                                   __HIP_MEMORY_SCOPE_AGENT);
        } else {
            while (__hip_atomic_load(&bar[1], __ATOMIC_ACQUIRE,
                                     __HIP_MEMORY_SCOPE_AGENT) < gen)
                __builtin_amdgcn_s_sleep(1);
        }
    }
    __syncthreads();
}

__global__ __launch_bounds__(THREADS, 4)
void sinkhorn_persistent(const float* __restrict__ s0,
                         _Float16* __restrict__ sh,
                         float* __restrict__ upA,
                         float* __restrict__ upB,
                         unsigned* __restrict__ bar,
                         float* __restrict__ out)
{
    const int bid = blockIdx.x, t = threadIdx.x;
    const int b = bid % B_, chunk = bid / B_;
    const int i0 = chunk * ICHUNK;

    __shared__ float rS[ICHUNK];
    __shared__ float vS[ICHUNK];
    __shared__ float cS[M_];

    const size_t base4 = ((size_t)b * N_ + i0) * (M_ / 4);  // 4-elem groups
    const size_t upOff = ((size_t)b * NCHUNKS + chunk) * M_;

    // ---- phase k=0: read fp32 slice, emit fp16 copy, colsum partials (r=1)
    {
        const f32x4* s4 = reinterpret_cast<const f32x4*>(s0) + base4;
        half4v*      o4 = reinterpret_cast<half4v*>(sh) + base4;
        f32x4 acc = {0.f, 0.f, 0.f, 0.f};
        #pragma unroll 4
        for (int i = 0; i < ICHUNK; ++i) {
            const f32x4 sv = s4[(size_t)i * (M_ / 4) + t];
            acc += sv;
            half4v h;
            h[0] = (_Float16)sv.x; h[1] = (_Float16)sv.y;
            h[2] = (_Float16)sv.z; h[3] = (_Float16)sv.w;
            o4[(size_t)i * (M_ / 4) + t] = h;
        }
        reinterpret_cast<f32x4*>(upA + upOff)[t] = acc;
    }
    if (t < ICHUNK) rS[t] = 1.0f;
    f32x4 cp4 = {1.f, 1.f, 1.f, 1.f};

    unsigned gen = 1;
    gridBarrier(bar, gen++);

    const float* upR = upA;   // read buffer (last colsum output)
    float*       upW = upB;   // write buffer (this colsum output)

    const half8v* sbase8 =
        reinterpret_cast<const half8v*>(sh) + (size_t)b * N_ * (M_ / 8);
    const half4v* sbase4 = reinterpret_cast<const half4v*>(sh) + base4;
    const int wave = t >> 6, lane = t & 63;

    #pragma unroll 1
    for (int pair = 0; pair < 7; ++pair) {
        // ---- rowsum phase (odd k): u from upR; c update; v for own rows
        {
            f32x4 u4 = {0.f, 0.f, 0.f, 0.f};
            const f32x4* up =
                reinterpret_cast<const f32x4*>(upR + (size_t)b * NCHUNKS * M_);
            #pragma unroll 8
            for (int ch = 0; ch < NCHUNKS; ++ch)
                u4 += up[ch * (M_ / 4) + t];
            f32x4 c4;
            c4.x = cp4.x / (cp4.x * u4.x + EPSF);
            c4.y = cp4.y / (cp4.y * u4.y + EPSF);
            c4.z = cp4.z / (cp4.z * u4.z + EPSF);
            c4.w = cp4.w / (cp4.w * u4.w + EPSF);
            cp4 = c4;
            reinterpret_cast<f32x4*>(cS)[t] = c4;
        }
        __syncthreads();
        {
            const f32x4* cS4 = reinterpret_cast<const f32x4*>(cS);
            f32x4 creg[2][2];
            #pragma unroll
            for (int q = 0; q < 2; ++q) {
                creg[q][0] = cS4[2 * (q * 64 + lane)];
                creg[q][1] = cS4[2 * (q * 64 + lane) + 1];
            }
            #pragma unroll 2
            for (int rw = 0; rw < ICHUNK / 4; ++rw) {
                const int il = wave * (ICHUNK / 4) + rw;    // local row 0..31
                const half8v* row = sbase8 + (size_t)(i0 + il) * (M_ / 8);
                float sum = 0.f;
                #pragma unroll
                for (int q = 0; q < 2; ++q) {
                    const half8v s8 = row[q * 64 + lane];
                    sum += (float)s8[0] * creg[q][0].x + (float)s8[1] * creg[q][0].y
                         + (float)s8[2] * creg[q][0].z + (float)s8[3] * creg[q][0].w
                         + (float)s8[4] * creg[q][1].x + (float)s8[5] * creg[q][1].y
                         + (float)s8[6] * creg[q][1].z + (float)s8[7] * creg[q][1].w;
                }
                #pragma unroll
                for (int off = 32; off > 0; off >>= 1)
                    sum += __shfl_down(sum, off, 64);
                if (lane == 0) vS[il] = sum;
            }
        }
        __syncthreads();
        // ---- colsum phase (even k): r update (block-local!), partials -> upW
        if (t < ICHUNK) rS[t] = rS[t] / (rS[t] * vS[t] + EPSF);
        __syncthreads();
        {
            f32x4 acc = {0.f, 0.f, 0.f, 0.f};
            #pragma unroll 8
            for (int i = 0; i < ICHUNK; ++i) {
                const float  r  = rS[i];                 // LDS broadcast
                const half4v s4 = sbase4[(size_t)i * (M_ / 4) + t];
                acc.x += r * (float)s4[0]; acc.y += r * (float)s4[1];
                acc.z += r * (float)s4[2]; acc.w += r * (float)s4[3];
            }
            reinterpret_cast<f32x4*>(upW + upOff)[t] = acc;
        }
        gridBarrier(bar, gen++);
        float* tmp = const_cast<float*>(upR); upR = upW; upW = tmp;
    }

    // ---- final: u14 from upR; c15 = c13/(c13*u14+eps); out = r14*sh*c15
    {
        f32x4 u4 = {0.f, 0.f, 0.f, 0.f};
        const f32x4* up =
            reinterpret_cast<const f32x4*>(upR + (size_t)b * NCHUNKS * M_);
        #pragma unroll 8
        for (int ch = 0; ch < NCHUNKS; ++ch)
            u4 += up[ch * (M_ / 4) + t];
        f32x4 c4;
        c4.x = cp4.x / (cp4.x * u4.x + EPSF);
        c4.y = cp4.y / (cp4.y * u4.y + EPSF);
        c4.z = cp4.z / (cp4.z * u4.z + EPSF);
        c4.w = cp4.w / (cp4.w * u4.w + EPSF);

        f32x4* op = reinterpret_cast<f32x4*>(out) + base4;
        #pragma unroll 4
        for (int i = 0; i < ICHUNK; ++i) {
            const float  r  = rS[i];
            const half4v s4 = sbase4[(size_t)i * (M_ / 4) + t];
            f32x4 o;
            o.x = r * (float)s4[0] * c4.x;
            o.y = r * (float)s4[1] * c4.y;
            o.z = r * (float)s4[2] * c4.z;
            o.w = r * (float)s4[3] * c4.w;
            __builtin_nontemporal_store(o, op + (size_t)i * (M_ / 4) + t);
        }
    }
}

// ===========================================================================
extern "C" void kernel_launch(void* const* d_in, const int* in_sizes, int n_in,
                              void* d_out, int out_size, void* d_ws, size_t ws_size,
                              hipStream_t stream)
{
    const float* s0  = (const float*)d_in[0];
    float*       out = (float*)d_out;

    // workspace: sh (64 MiB) | upA (4 MB) | upB (4 MB) | bar (2 u32)
    // ws_size evidenced at 512 MiB (round-6 poison fill) -- ample.
    constexpr size_t F16_BYTES = (size_t)B_ * N_ * M_ * 2;
    constexpr size_t UP_FLOATS = (size_t)B_ * NCHUNKS * M_;
    _Float16* sh  = (_Float16*)d_ws;
    float*    upA = (float*)((char*)d_ws + F16_BYTES);
    float*    upB = upA + UP_FLOATS;
    unsigned* bar = (unsigned*)(upB + UP_FLOATS);

    // barrier state is poisoned 0xAA before every timed launch -> zero it
    hipMemsetAsync(bar, 0, 2 * sizeof(unsigned), stream);

    sinkhorn_persistent<<<dim3(NBLOCKS), dim3(THREADS), 0, stream>>>(
        s0, sh, upA, upB, bar, out);
}